// Round 2
// baseline (5142.302 us; speedup 1.0000x reference)
//
#include <hip/hip_runtime.h>
#include <hip/hip_bf16.h>
#include <type_traits>

#define DEV __device__ __forceinline__

static constexpr float LOG2E = 1.44269504088896340736f;
static constexpr float C2E   = 2.88539008177792681472f; // 2*log2(e)

DEV float rcpf_(float x){ return __builtin_amdgcn_rcpf(x); }
DEV float exp2f_(float x){ return __builtin_amdgcn_exp2f(x); }
DEV float sigmoidf_(float x){ return rcpf_(1.f + exp2f_(-LOG2E*x)); }
DEV float tanhf_fast(float x){ return 1.f - 2.f*rcpf_(exp2f_(C2E*x) + 1.f); }

DEV void  st_val(float* p, float v){ *p = v; }
DEV void  st_val(__hip_bfloat16* p, float v){ *p = __float2bfloat16(v); }
DEV float ld_val(const float* p){ return *p; }
DEV float ld_val(const __hip_bfloat16* p){ return __bfloat162float(*p); }
DEV float bfl(unsigned u){ return __uint_as_float(u << 16); }
DEV float bfh(unsigned u){ return __uint_as_float(u & 0xffff0000u); }

// ---------------------------------------------------------------------------
// K1: E[(l*64+b)*128 + h] = exp(2*(passEnc[l,b,:]·Wp[h,:] + Wp_b[h]))
// ---------------------------------------------------------------------------
template<typename ET>
__global__ __launch_bounds__(256,4) void k_projE(const float* __restrict__ pe,
      const float* __restrict__ W, const float* __restrict__ bias,
      ET* __restrict__ E){
  __shared__ __align__(16) float xs[32*256];
  const int tid = threadIdx.x;
  const long r0 = (long)blockIdx.x * 32;
  const float4* src = (const float4*)(pe + r0*256);
  float4* dst = (float4*)xs;
  #pragma unroll
  for (int i=0;i<8;i++) dst[tid + 256*i] = src[tid + 256*i];
  __syncthreads();
  const int h = tid & 127, g = tid >> 7;
  float acc[16];
  #pragma unroll
  for (int r=0;r<16;r++) acc[r] = 0.f;
  for (int kc=0; kc<8; kc++){
    float4 w4[8];
    const float4* wp = (const float4*)(W + h*256 + kc*32);
    #pragma unroll
    for (int q=0;q<8;q++) w4[q] = wp[q];
    #pragma unroll
    for (int r=0;r<16;r++){
      const float4* xr = (const float4*)(xs + (g*16+r)*256 + kc*32);
      #pragma unroll
      for (int q=0;q<8;q++){
        const float4 xv = xr[q];
        acc[r] += xv.x*w4[q].x + xv.y*w4[q].y + xv.z*w4[q].z + xv.w*w4[q].w;
      }
    }
  }
  const float bh = bias[h];
  #pragma unroll
  for (int r=0;r<16;r++)
    st_val(&E[(r0 + g*16 + r)*128 + h], exp2f_(C2E*(acc[r] + bh)));
}

// ---------------------------------------------------------------------------
// K2: fused scores + online softmax + context + gate + GI GEMMs.
// Block = (b, 32-t tile). S[t,l] = -2*sum_h v[h]/(E_l[h]*F_t[h]+1)
// Epilogue: cc=[x,c]; g=sigmoid(cc@Wg.T+b); ctx=g*cc;
//           GIf[t] = ctx@wihf.T+bihf ; GIr[1023-t] = ctx@wihr.T+bihr
// ---------------------------------------------------------------------------
#define OF_F   0        // [32][132]
#define OF_V   4224     // [128]
#define OF_M   4352     // [32]
#define OF_SU  4384     // [32]
#define OF_R   4416     // [32]
#define OF_S   4448     // [32][33]
#define OF_E   5504     // [32][132]  (staging also reuses this as x rows [32][256])
#define OF_PE  9728     // [32][260]
#define LDS_FLOATS 18048

template<typename ET, typename GIT>
__global__ __launch_bounds__(256,2) void k_attn_gates(const float* __restrict__ pe,
      const ET* __restrict__ E, const float* __restrict__ Wph,
      const float* __restrict__ Wphb, const float* __restrict__ Vt,
      const float* __restrict__ Wg, const float* __restrict__ Wgb,
      const float* __restrict__ wihf, const float* __restrict__ bihf,
      const float* __restrict__ wihr, const float* __restrict__ bihr,
      GIT* __restrict__ GIf, GIT* __restrict__ GIr){
  __shared__ __align__(16) float lds[LDS_FLOATS];
  const int tid = threadIdx.x;
  const int b  = blockIdx.x & 63;
  const int tt = blockIdx.x >> 6;
  const int t0 = tt * 32;

  // stage x rows, v, init softmax state
  {
    float* xsf = lds + OF_E;
    for (int i = tid; i < 32*64; i += 256){
      const int t = i >> 6, c4 = i & 63;
      *(float4*)(xsf + t*256 + c4*4) =
        *(const float4*)(pe + ((long)(t0+t)*64 + b)*256 + c4*4);
    }
    if (tid < 128) lds[OF_V + tid] = Vt[b*128 + tid];
    if (tid < 32){ lds[OF_M+tid] = -__builtin_inff(); lds[OF_SU+tid] = 0.f; }
  }
  __syncthreads();
  // F[t][h] = exp(2*(x_t·Wph[h]+Wphb[h]))
  {
    const float* xsf = lds + OF_E;
    const int h = tid & 127, g = tid >> 7;
    float acc[16];
    #pragma unroll
    for (int r=0;r<16;r++) acc[r]=0.f;
    for (int kc=0; kc<8; kc++){
      float4 w4[8];
      const float4* wp = (const float4*)(Wph + h*256 + kc*32);
      #pragma unroll
      for (int q=0;q<8;q++) w4[q] = wp[q];
      #pragma unroll
      for (int r=0;r<16;r++){
        const float4* xr = (const float4*)(xsf + (g*16+r)*256 + kc*32);
        #pragma unroll
        for (int q=0;q<8;q++){
          const float4 xv = xr[q];
          acc[r] += xv.x*w4[q].x + xv.y*w4[q].y + xv.z*w4[q].z + xv.w*w4[q].w;
        }
      }
    }
    const float bh = Wphb[h];
    __syncthreads();
    #pragma unroll
    for (int r=0;r<16;r++)
      lds[OF_F + (g*16+r)*132 + h] = exp2f_(C2E*(acc[r] + bh));
  }
  float cacc[4][8];
  #pragma unroll
  for (int i=0;i<4;i++)
    #pragma unroll
    for (int q=0;q<8;q++) cacc[i][q]=0.f;
  const int tg = tid >> 4, lg = tid & 15;     // phase S mapping (2t x 2l)
  const int tgrp = tid & 7, dgrp = tid >> 3;  // phase C mapping (4t x 8d)
  __syncthreads();

  for (int lt=0; lt<32; lt++){
    const int l0 = lt*32;
    __syncthreads();  // prev phase C done before tile reload
    if constexpr (std::is_same<ET,float>::value){
      for (int i = tid; i < 32*32; i += 256){
        const int l = i >> 5, c4 = i & 31;
        *(float4*)(lds + OF_E + l*132 + c4*4) =
          *(const float4*)(E + ((long)(l0+l)*64 + b)*128 + c4*4);
      }
    } else {
      for (int i = tid; i < 32*16; i += 256){
        const int l = i >> 4, c8 = i & 15;
        const uint4 w = *(const uint4*)(E + (((long)(l0+l)*64 + b)*128 + c8*8));
        float4 f0, f1;
        f0.x=bfl(w.x); f0.y=bfh(w.x); f0.z=bfl(w.y); f0.w=bfh(w.y);
        f1.x=bfl(w.z); f1.y=bfh(w.z); f1.z=bfl(w.w); f1.w=bfh(w.w);
        *(float4*)(lds + OF_E + l*132 + c8*8)     = f0;
        *(float4*)(lds + OF_E + l*132 + c8*8 + 4) = f1;
      }
    }
    for (int i = tid; i < 32*64; i += 256){
      const int l = i >> 6, c4 = i & 63;
      *(float4*)(lds + OF_PE + l*260 + c4*4) =
        *(const float4*)(pe + ((long)(l0+l)*64 + b)*256 + c4*4);
    }
    __syncthreads();
    // phase S
    {
      float s00=0.f, s01=0.f, s10=0.f, s11=0.f;
      const float* Fb = lds + OF_F + (tg*2)*132;
      const float* Eb = lds + OF_E + (lg*2)*132;
      const float* Vb = lds + OF_V;
      #pragma unroll 4
      for (int hc=0; hc<32; hc++){
        const float4 f0 = *(const float4*)(Fb + hc*4);
        const float4 f1 = *(const float4*)(Fb + 132 + hc*4);
        const float4 e0 = *(const float4*)(Eb + hc*4);
        const float4 e1 = *(const float4*)(Eb + 132 + hc*4);
        const float4 vv = *(const float4*)(Vb + hc*4);
        s00 += vv.x*rcpf_(f0.x*e0.x+1.f); s00 += vv.y*rcpf_(f0.y*e0.y+1.f);
        s00 += vv.z*rcpf_(f0.z*e0.z+1.f); s00 += vv.w*rcpf_(f0.w*e0.w+1.f);
        s01 += vv.x*rcpf_(f0.x*e1.x+1.f); s01 += vv.y*rcpf_(f0.y*e1.y+1.f);
        s01 += vv.z*rcpf_(f0.z*e1.z+1.f); s01 += vv.w*rcpf_(f0.w*e1.w+1.f);
        s10 += vv.x*rcpf_(f1.x*e0.x+1.f); s10 += vv.y*rcpf_(f1.y*e0.y+1.f);
        s10 += vv.z*rcpf_(f1.z*e0.z+1.f); s10 += vv.w*rcpf_(f1.w*e0.w+1.f);
        s11 += vv.x*rcpf_(f1.x*e1.x+1.f); s11 += vv.y*rcpf_(f1.y*e1.y+1.f);
        s11 += vv.z*rcpf_(f1.z*e1.z+1.f); s11 += vv.w*rcpf_(f1.w*e1.w+1.f);
      }
      lds[OF_S + (tg*2+0)*33 + (lg*2+0)] = -2.f*s00;
      lds[OF_S + (tg*2+0)*33 + (lg*2+1)] = -2.f*s01;
      lds[OF_S + (tg*2+1)*33 + (lg*2+0)] = -2.f*s10;
      lds[OF_S + (tg*2+1)*33 + (lg*2+1)] = -2.f*s11;
    }
    __syncthreads();
    // online softmax
    {
      const int t = tid >> 3, sub = tid & 7;
      float* Srow = lds + OF_S + t*33 + sub*4;
      const float s0=Srow[0], s1=Srow[1], s2=Srow[2], s3=Srow[3];
      float mx = fmaxf(fmaxf(s0,s1), fmaxf(s2,s3));
      #pragma unroll
      for (int off=1; off<8; off<<=1) mx = fmaxf(mx, __shfl_xor(mx, off));
      const float m_old = lds[OF_M + t];
      const float m_new = fmaxf(m_old, mx);
      const float p0 = exp2f_(LOG2E*(s0-m_new));
      const float p1 = exp2f_(LOG2E*(s1-m_new));
      const float p2 = exp2f_(LOG2E*(s2-m_new));
      const float p3 = exp2f_(LOG2E*(s3-m_new));
      float ps = p0+p1+p2+p3;
      #pragma unroll
      for (int off=1; off<8; off<<=1) ps += __shfl_xor(ps, off);
      Srow[0]=p0; Srow[1]=p1; Srow[2]=p2; Srow[3]=p3;
      if (sub==0){
        const float rsc = exp2f_(LOG2E*(m_old - m_new));
        lds[OF_R + t] = rsc;
        lds[OF_SU + t] = lds[OF_SU + t]*rsc + ps;
        lds[OF_M + t] = m_new;
      }
    }
    __syncthreads();
    // phase C
    {
      #pragma unroll
      for (int i=0;i<4;i++){
        const float rs = lds[OF_R + tgrp*4 + i];
        #pragma unroll
        for (int q=0;q<8;q++) cacc[i][q] *= rs;
      }
      const float* Pb  = lds + OF_S + (tgrp*4)*33;
      const float* PEb = lds + OF_PE + dgrp*8;
      #pragma unroll 4
      for (int l=0; l<32; l++){
        const float p0 = Pb[l], p1 = Pb[33+l], p2 = Pb[66+l], p3 = Pb[99+l];
        const float4 qa = *(const float4*)(PEb + l*260);
        const float4 qb = *(const float4*)(PEb + l*260 + 4);
        cacc[0][0]+=p0*qa.x; cacc[0][1]+=p0*qa.y; cacc[0][2]+=p0*qa.z; cacc[0][3]+=p0*qa.w;
        cacc[0][4]+=p0*qb.x; cacc[0][5]+=p0*qb.y; cacc[0][6]+=p0*qb.z; cacc[0][7]+=p0*qb.w;
        cacc[1][0]+=p1*qa.x; cacc[1][1]+=p1*qa.y; cacc[1][2]+=p1*qa.z; cacc[1][3]+=p1*qa.w;
        cacc[1][4]+=p1*qb.x; cacc[1][5]+=p1*qb.y; cacc[1][6]+=p1*qb.z; cacc[1][7]+=p1*qb.w;
        cacc[2][0]+=p2*qa.x; cacc[2][1]+=p2*qa.y; cacc[2][2]+=p2*qa.z; cacc[2][3]+=p2*qa.w;
        cacc[2][4]+=p2*qb.x; cacc[2][5]+=p2*qb.y; cacc[2][6]+=p2*qb.z; cacc[2][7]+=p2*qb.w;
        cacc[3][0]+=p3*qa.x; cacc[3][1]+=p3*qa.y; cacc[3][2]+=p3*qa.z; cacc[3][3]+=p3*qa.w;
        cacc[3][4]+=p3*qb.x; cacc[3][5]+=p3*qb.y; cacc[3][6]+=p3*qb.z; cacc[3][7]+=p3*qb.w;
      }
    }
  }
  // ---- epilogue: gates + GI ----
  __syncthreads();
  float inv[4];
  #pragma unroll
  for (int i=0;i<4;i++) inv[i] = rcpf_(lds[OF_SU + tgrp*4 + i]);
  __syncthreads();   // all SU reads done before cc overwrites lds
  // build cc[32][520] at lds[0..16640)
  for (int i = tid; i < 32*64; i += 256){
    const int r = i >> 6, c4 = i & 63;
    *(float4*)(lds + r*520 + c4*4) =
      *(const float4*)(pe + ((long)(t0+r)*64 + b)*256 + c4*4);
  }
  #pragma unroll
  for (int i=0;i<4;i++){
    const int r = tgrp*4 + i;
    float4 o0, o1;
    o0.x=cacc[i][0]*inv[i]; o0.y=cacc[i][1]*inv[i]; o0.z=cacc[i][2]*inv[i]; o0.w=cacc[i][3]*inv[i];
    o1.x=cacc[i][4]*inv[i]; o1.y=cacc[i][5]*inv[i]; o1.z=cacc[i][6]*inv[i]; o1.w=cacc[i][7]*inv[i];
    *(float4*)(lds + r*520 + 256 + dgrp*8)     = o0;
    *(float4*)(lds + r*520 + 256 + dgrp*8 + 4) = o1;
  }
  __syncthreads();
  // GEMM1: gate
  {
    float a0[32], a1[32];
    #pragma unroll
    for (int r=0;r<32;r++){ a0[r]=0.f; a1[r]=0.f; }
    const float* w0 = Wg + (long)tid*512;
    const float* w1 = Wg + (long)(tid+256)*512;
    for (int kc=0; kc<32; kc++){
      float4 wa[4], wb[4];
      #pragma unroll
      for (int q=0;q<4;q++){
        wa[q] = *(const float4*)(w0 + kc*16 + q*4);
        wb[q] = *(const float4*)(w1 + kc*16 + q*4);
      }
      #pragma unroll 8
      for (int r=0;r<32;r++){
        const float4* xr = (const float4*)(lds + r*520 + kc*16);
        #pragma unroll
        for (int q=0;q<4;q++){
          const float4 x = xr[q];
          a0[r] += x.x*wa[q].x + x.y*wa[q].y + x.z*wa[q].z + x.w*wa[q].w;
          a1[r] += x.x*wb[q].x + x.y*wb[q].y + x.z*wb[q].z + x.w*wb[q].w;
        }
      }
    }
    const float b0 = Wgb[tid], b1 = Wgb[tid+256];
    __syncthreads();
    #pragma unroll 8
    for (int r=0;r<32;r++){
      lds[r*520 + tid]       *= sigmoidf_(a0[r] + b0);
      lds[r*520 + tid + 256] *= sigmoidf_(a1[r] + b1);
    }
  }
  __syncthreads();
  // GEMM2: 768 output columns (384 fwd + 384 rev)
  for (int p=0; p<3; p++){
    const int j = tid + p*256;
    const bool isf = (j < 384);
    const float* wrow = isf ? (wihf + (long)j*512) : (wihr + (long)(j-384)*512);
    const float bb = isf ? bihf[j] : bihr[j-384];
    float a[32];
    #pragma unroll
    for (int r=0;r<32;r++) a[r]=0.f;
    for (int kc=0; kc<32; kc++){
      float4 wv[4];
      #pragma unroll
      for (int q=0;q<4;q++) wv[q] = *(const float4*)(wrow + kc*16 + q*4);
      #pragma unroll 8
      for (int r=0;r<32;r++){
        const float4* xr = (const float4*)(lds + r*520 + kc*16);
        #pragma unroll
        for (int q=0;q<4;q++){
          const float4 x = xr[q];
          a[r] += x.x*wv[q].x + x.y*wv[q].y + x.z*wv[q].z + x.w*wv[q].w;
        }
      }
    }
    #pragma unroll 4
    for (int r=0;r<32;r++){
      const long t = t0 + r;
      const float val = a[r] + bb;
      if (isf) st_val(&GIf[(t*64 + b)*384 + j], val);
      else     st_val(&GIr[((1023 - t)*64 + b)*384 + (j-384)], val);
    }
  }
}

// ---------------------------------------------------------------------------
// K3: GRU recurrences. 128 blocks = (dir, b). whh weight-stationary in VGPRs.
// ---------------------------------------------------------------------------
template<typename GIT>
__global__ __launch_bounds__(384,2) void k_gru(const GIT* __restrict__ GIf, const GIT* __restrict__ GIr,
      const float* __restrict__ whhf, const float* __restrict__ bhhf,
      const float* __restrict__ whhr, const float* __restrict__ bhhr,
      const float* __restrict__ h0f, const float* __restrict__ h0r,
      float* __restrict__ out){
  const int d = blockIdx.x >> 6, b = blockIdx.x & 63;
  const GIT*  GI  = d ? GIr  : GIf;
  const float* whh = d ? whhr : whhf;
  const float* bhh = d ? bhhr : bhhf;
  const float* h0  = d ? h0r  : h0f;
  const int j = threadIdx.x;
  __shared__ __align__(16) float hsh[128];
  __shared__ float sA[256];
  __shared__ float sGin[128];
  __shared__ float sGhn[128];
  if (j < 128) hsh[j] = h0[b*128 + j];
  float4 w4[32];
  const float4* wr = (const float4*)(whh + (long)j*128);
  #pragma unroll
  for (int q=0;q<32;q++) w4[q] = wr[q];
  const float bj = bhh[j];
  __syncthreads();
  float gi_next = ld_val(&GI[(long)b*384 + j]);
  for (int t=0; t<1024; t++){
    const float gi = gi_next;
    if (t < 1023) gi_next = ld_val(&GI[((long)(t+1)*64 + b)*384 + j]);
    float gh = bj;
    #pragma unroll
    for (int q=0;q<32;q++){
      const float4 hv = *(const float4*)(hsh + q*4);
      gh += w4[q].x*hv.x + w4[q].y*hv.y + w4[q].z*hv.z + w4[q].w*hv.w;
    }
    if (j < 256) sA[j] = gi + gh;
    else { sGin[j-256] = gi; sGhn[j-256] = gh; }
    __syncthreads();
    if (j < 128){
      const float r = sigmoidf_(sA[j]);
      const float z = sigmoidf_(sA[128+j]);
      const float n = tanhf_fast(sGin[j] + r*sGhn[j]);
      const float hnew = (1.f - z)*n + z*hsh[j];
      hsh[j] = hnew;
      out[((long)t*64 + b)*256 + d*128 + j] = hnew;
    }
    __syncthreads();
  }
}

__global__ void k_sentinel(float* out){ out[0] = 1.0e6f; }

// ---------------------------------------------------------------------------
extern "C" void kernel_launch(void* const* d_in, const int* in_sizes, int n_in,
                              void* d_out, int out_size, void* d_ws, size_t ws_size,
                              hipStream_t stream){
  const float* passEnc = (const float*)d_in[0];
  const float* Wp_w  = (const float*)d_in[1];
  const float* Wp_b  = (const float*)d_in[2];
  const float* Wph_w = (const float*)d_in[3];
  const float* Wph_b = (const float*)d_in[4];
  const float* Wg_w  = (const float*)d_in[5];
  const float* Wg_b  = (const float*)d_in[6];
  const float* Vt    = (const float*)d_in[7];
  const float* wih_f = (const float*)d_in[8];
  const float* whh_f = (const float*)d_in[9];
  const float* bih_f = (const float*)d_in[10];
  const float* bhh_f = (const float*)d_in[11];
  const float* wih_r = (const float*)d_in[12];
  const float* whh_r = (const float*)d_in[13];
  const float* bih_r = (const float*)d_in[14];
  const float* bhh_r = (const float*)d_in[15];
  const float* h0f   = (const float*)d_in[16];
  const float* h0r   = (const float*)d_in[17];
  float* out = (float*)d_out;
  using bf16 = __hip_bfloat16;

  const size_t nE  = 8388608ull;   // L*B*H
  const size_t nGI = 25165824ull;  // L*B*3H
  char* base = (char*)d_ws;

  if (ws_size >= nE*4 + 2*nGI*4){
    // tier 1: E f32, GI f32 (224 MiB)
    float* E   = (float*)base;
    float* GIf = (float*)(base + nE*4);
    float* GIr = GIf + nGI;
    k_projE<float><<<2048,256,0,stream>>>(passEnc, Wp_w, Wp_b, E);
    k_attn_gates<float,float><<<2048,256,0,stream>>>(passEnc, E, Wph_w, Wph_b, Vt,
        Wg_w, Wg_b, wih_f, bih_f, wih_r, bih_r, GIf, GIr);
    k_gru<float><<<128,384,0,stream>>>(GIf, GIr, whh_f, bhh_f, whh_r, bhh_r, h0f, h0r, out);
  } else if (ws_size >= nE*4 + 2*nGI*2){
    // tier 2: E f32, GI bf16 (128 MiB)
    float* E   = (float*)base;
    bf16* GIf  = (bf16*)(base + nE*4);
    bf16* GIr  = GIf + nGI;
    k_projE<float><<<2048,256,0,stream>>>(passEnc, Wp_w, Wp_b, E);
    k_attn_gates<float,bf16><<<2048,256,0,stream>>>(passEnc, E, Wph_w, Wph_b, Vt,
        Wg_w, Wg_b, wih_f, bih_f, wih_r, bih_r, GIf, GIr);
    k_gru<bf16><<<128,384,0,stream>>>(GIf, GIr, whh_f, bhh_f, whh_r, bhh_r, h0f, h0r, out);
  } else if (ws_size >= nE*2 + 2*nGI*2){
    // tier 3: E bf16, GI bf16 (112 MiB)
    bf16* E    = (bf16*)base;
    bf16* GIf  = (bf16*)(base + nE*2);
    bf16* GIr  = GIf + nGI;
    k_projE<bf16><<<2048,256,0,stream>>>(passEnc, Wp_w, Wp_b, E);
    k_attn_gates<bf16,bf16><<<2048,256,0,stream>>>(passEnc, E, Wph_w, Wph_b, Vt,
        Wg_w, Wg_b, wih_f, bih_f, wih_r, bih_r, GIf, GIr);
    k_gru<bf16><<<128,384,0,stream>>>(GIf, GIr, whh_f, bhh_f, whh_r, bhh_r, h0f, h0r, out);
  } else {
    // no tier fits: distinguishable sentinel (absmax will be ~1e6, not 2.65)
    k_sentinel<<<1,1,0,stream>>>(out);
  }
}